// Round 5
// baseline (605.940 us; speedup 1.0000x reference)
//
#include <hip/hip_runtime.h>

// RuleFilter: out[0] = logits[0]; out[i] = logits[i] * mask_table[argmax(out[i-1])]
// logits: (L=128, N=4096, V=128) fp32, mask_table: (128,128) fp32 {0,1}.
//
// R5: all prior variants ran the per-CU vmem pipe at half width (dwordx2 =
// 8 B/lane, forced by 512 B rows at 1 seq/wave) and plateaued at ~5.6 B/cy/CU
// = 55% of the m13 streaming ceiling (measured with 16 B/lane). This version
// gives each wave TWO adjacent sequences: row i of the pair is a contiguous
// 1 KB slab -> one global_load_dwordx4 / store_dwordx4 (16 B/lane) per row.
// Lanes 0..31 = seq A, 32..63 = seq B, 4 vocab elems/lane; argmax = two
// independent 32-lane DPP reductions + per-half ballots. Prefetch load is
// hoisted BEFORE the wait (ring has D+1 slots so the hoisted load never
// clobbers the row being consumed). Exact vmcnt ledger, never 0.

constexpr int V = 128;
constexpr int L = 128;
constexpr int N = 4096;
constexpr int D  = 16;      // rows in flight
constexpr int RD = D + 1;   // ring slots (hoisted prefetch needs +1)
constexpr unsigned ROWB = (unsigned)N * V * 4;  // 2 MiB between rows

typedef __attribute__((ext_vector_type(4))) float f32x4;

// Per-half max: DPP ladder stopping at row_bcast:15.
// Result: lane31 = max(lanes 0..31), lane63 = max(lanes 32..63).
__device__ __forceinline__ int halfmax_dpp(float x) {
    int v = __float_as_int(x);
    const int ninf = __float_as_int(-__builtin_inff());
#define RF_STEP(ctrl)                                                          \
    {                                                                          \
        int s = __builtin_amdgcn_update_dpp(ninf, v, ctrl, 0xf, 0xf, false);   \
        v = __float_as_int(fmaxf(__int_as_float(v), __int_as_float(s)));       \
    }
    RF_STEP(0x111)  // row_shr:1
    RF_STEP(0x112)  // row_shr:2
    RF_STEP(0x114)  // row_shr:4
    RF_STEP(0x118)  // row_shr:8  -> lane{15,31,47,63} hold row16 maxes
    RF_STEP(0x142)  // row_bcast:15 -> lane31 = maxA, lane63 = maxB
#undef RF_STEP
    return v;
}

// argmax within one 32-lane half from 4 per-elem ballot masks.
// Element index = 4*lane_local + k; ties -> lowest index.
__device__ __forceinline__ int argmax_half(unsigned m0, unsigned m1,
                                           unsigned m2, unsigned m3) {
    const int BIG = 1 << 30;
    int c0 = m0 ? (__builtin_ctz(m0) * 4 + 0) : BIG;
    int c1 = m1 ? (__builtin_ctz(m1) * 4 + 1) : BIG;
    int c2 = m2 ? (__builtin_ctz(m2) * 4 + 2) : BIG;
    int c3 = m3 ? (__builtin_ctz(m3) * 4 + 3) : BIG;
    return min(min(c0, c1), min(c2, c3));
}

// 16-way dynamic select (j may differ per lane; 15 cndmask levels).
__device__ __forceinline__ unsigned sel16(const unsigned* t, int j) {
    unsigned a0 = (j & 1) ? t[1]  : t[0];
    unsigned a1 = (j & 1) ? t[3]  : t[2];
    unsigned a2 = (j & 1) ? t[5]  : t[4];
    unsigned a3 = (j & 1) ? t[7]  : t[6];
    unsigned a4 = (j & 1) ? t[9]  : t[8];
    unsigned a5 = (j & 1) ? t[11] : t[10];
    unsigned a6 = (j & 1) ? t[13] : t[12];
    unsigned a7 = (j & 1) ? t[15] : t[14];
    unsigned b0 = (j & 2) ? a1 : a0;
    unsigned b1 = (j & 2) ? a3 : a2;
    unsigned b2 = (j & 2) ? a5 : a4;
    unsigned b3 = (j & 2) ? a7 : a6;
    unsigned c0 = (j & 4) ? b1 : b0;
    unsigned c1 = (j & 4) ? b3 : b2;
    return (j & 8) ? c1 : c0;
}

// Wave-uniform pointer -> SGPR-provable uniform value.
__device__ __forceinline__ unsigned long long uniform_u64(const void* p) {
    unsigned long long x = (unsigned long long)p;
    unsigned lo = __builtin_amdgcn_readfirstlane((unsigned)x);
    unsigned hi = __builtin_amdgcn_readfirstlane((unsigned)(x >> 32));
    return ((unsigned long long)hi << 32) | lo;
}

// One fully-unrolled pipeline step; all indices compile-time (SROA -> VGPRs).
template <int I>
struct Step {
    static __device__ __forceinline__ void run(f32x4* ring, f32x4* fbuf,
                                               const unsigned* tbl,
                                               int& pA, int& pB, bool hi,
                                               unsigned long long lbase,
                                               unsigned long long obase,
                                               unsigned laneoff) {
        constexpr int rs = I % RD;  // consume slot (also fbuf slot)
        // vmcnt ledger (issue order per step: load L_{I+D}, wait, store S_I):
        //  prologue (I<D): wait retires L_I; ops after it = D+I.
        //  I>=D: wait retires S_{I-D} (and older L_I) -> fbuf WAR safe;
        //        ops after S_{I-D} = (D-1) + min(D-1, L-1-I) + (I<=L-1-D ? 1:0)
        //        = 2D-1 steady, D-1+(L-1-I) in the tail.
        constexpr int NW = (I < D) ? (D + I)
            : (D - 1 + ((L - 1 - I) < (D - 1) ? (L - 1 - I) : (D - 1))
                     + ((I <= L - 1 - D) ? 1 : 0));

        // Hoisted prefetch: issues even if this wave is about to stall on the
        // wait. Slot (I+D)%RD != rs because D % RD != 0.
        if constexpr (I + D < L) {
            constexpr int ps = (I + D) % RD;
            unsigned voff = (unsigned)(I + D) * ROWB + laneoff;
            asm volatile("global_load_dwordx4 %0, %1, %2"
                         : "=&v"(ring[ps])
                         : "v"(voff), "s"(lbase));
        }

        // Ties: ring[rs] out/in -> consumers ordered after the wait;
        // fbuf[rs] in -> old store data stays alive until its store retires.
        asm volatile("s_waitcnt vmcnt(%c2)"
                     : "+v"(ring[rs])
                     : "v"(fbuf[rs]), "i"(NW));

        f32x4 c = ring[rs];
        f32x4 f;
        if constexpr (I == 0) {
            f = c;  // row 0 passes through unfiltered
        } else {
            int pv = hi ? pB : pA;  // per-lane prev index (per-half value)
            unsigned word  = sel16(tbl, pv >> 3);
            unsigned fbits = word >> ((pv & 7) * 4);
            f.x = (fbits & 1u) ? c.x : 0.0f;
            f.y = (fbits & 2u) ? c.y : 0.0f;
            f.z = (fbits & 4u) ? c.z : 0.0f;
            f.w = (fbits & 8u) ? c.w : 0.0f;
        }
        fbuf[rs] = f;

        {
            unsigned voff = (unsigned)I * ROWB + laneoff;
            asm volatile("global_store_dwordx4 %0, %1, %2"
                         :
                         : "v"(voff), "v"(fbuf[rs]), "s"(obase));
        }

        // Two independent 32-lane argmaxes.
        int mv  = halfmax_dpp(fmaxf(fmaxf(f.x, f.y), fmaxf(f.z, f.w)));
        int bvA = __builtin_amdgcn_readlane(mv, 31);
        int bvB = __builtin_amdgcn_readlane(mv, 63);
        float bv = hi ? __int_as_float(bvB) : __int_as_float(bvA);
        unsigned long long e0 = __ballot(f.x == bv);
        unsigned long long e1 = __ballot(f.y == bv);
        unsigned long long e2 = __ballot(f.z == bv);
        unsigned long long e3 = __ballot(f.w == bv);
        pA = argmax_half((unsigned)e0, (unsigned)e1, (unsigned)e2, (unsigned)e3);
        pB = argmax_half((unsigned)(e0 >> 32), (unsigned)(e1 >> 32),
                         (unsigned)(e2 >> 32), (unsigned)(e3 >> 32));

        Step<I + 1>::run(ring, fbuf, tbl, pA, pB, hi, lbase, obase, laneoff);
    }
};
template <>
struct Step<L> {
    static __device__ __forceinline__ void run(f32x4*, f32x4*, const unsigned*,
                                               int&, int&, bool,
                                               unsigned long long,
                                               unsigned long long, unsigned) {}
};

__global__ __launch_bounds__(256, 2) void rule_filter_kernel(
    const float* __restrict__ logits,      // (L, N, V)
    const float* __restrict__ mask_table,  // (V, V)
    float* __restrict__ out)               // (L, N, V)
{
    const int wave = threadIdx.x >> 6;  // 0..3
    const int lane = threadIdx.x & 63;  // 0..63
    const int ll   = lane & 31;         // lane within half
    const bool hi  = lane >= 32;
    const int pair = (blockIdx.x << 2) + wave;  // 0..2047: seqs {2p, 2p+1}

    // Row i of the pair = contiguous 1 KiB at pair*1024 + i*ROWB.
    const unsigned long long lbase = uniform_u64(logits + (size_t)pair * 2 * V);
    const unsigned long long obase = uniform_u64(out    + (size_t)pair * 2 * V);
    const unsigned laneoff = (unsigned)lane * 16;  // dwordx4 per lane

    // Per-lane mask table: tbl[j] bits[4r..4r+3] = mask_table[8j+r][4*ll..4*ll+3]
    unsigned tbl[16];
#pragma unroll 1
    for (int j = 0; j < 16; ++j) {
        unsigned acc = 0;
#pragma unroll
        for (int r = 0; r < 8; ++r) {
            const int p = j * 8 + r;
            float4 mv = *(const float4*)(mask_table + (size_t)p * V + ll * 4);
            unsigned bits = (mv.x != 0.0f ? 1u : 0u) | (mv.y != 0.0f ? 2u : 0u)
                          | (mv.z != 0.0f ? 4u : 0u) | (mv.w != 0.0f ? 8u : 0u);
            acc |= bits << (4 * r);
        }
        tbl[j] = acc;
    }
    // Drain table loads so the hand-counted vmcnt ledger is exact.
    asm volatile("s_waitcnt vmcnt(0)" ::: "memory");

    f32x4 ring[RD];
    f32x4 fbuf[RD];
#pragma unroll
    for (int r = 0; r < RD; ++r) { fbuf[r].x = 0.0f; fbuf[r].y = 0.0f;
                                   fbuf[r].z = 0.0f; fbuf[r].w = 0.0f; }

    // Prologue: rows 0..D-1 into ring[0..D-1] (vmcnt ops 1..D in order).
#pragma unroll
    for (int r = 0; r < D; ++r) {
        unsigned voff = (unsigned)r * ROWB + laneoff;
        asm volatile("global_load_dwordx4 %0, %1, %2"
                     : "=&v"(ring[r])
                     : "v"(voff), "s"(lbase));
    }

    int pA = 0, pB = 0;
    Step<0>::run(ring, fbuf, tbl, pA, pB, hi, lbase, obase, laneoff);
}

extern "C" void kernel_launch(void* const* d_in, const int* in_sizes, int n_in,
                              void* d_out, int out_size, void* d_ws, size_t ws_size,
                              hipStream_t stream) {
    const float* logits     = (const float*)d_in[0];  // (L, N, V) fp32
    const float* mask_table = (const float*)d_in[1];  // (V, V) fp32
    float* out              = (float*)d_out;          // (L, N, V) fp32

    dim3 grid(N / 8);  // 2048 waves, one per sequence-pair, 4 waves/block
    dim3 block(256);
    rule_filter_kernel<<<grid, block, 0, stream>>>(logits, mask_table, out);
}

// Round 6
// 461.600 us; speedup vs baseline: 1.3127x; 1.3127x over previous
//
#include <hip/hip_runtime.h>

// RuleFilter: out[0] = logits[0]; out[i] = logits[i] * mask_table[argmax(out[i-1])]
// logits: (L=128, N=4096, V=128) fp32, mask_table: (128,128) fp32 {0,1}.
//
// R6: measured invariant across R0-R5: per-wave streaming rate is capped at
// ~0.86 GB/s r+w regardless of ring depth/width/structure (R5 doubled bytes
// per wave, halved waves -> exactly 2x slower). Total BW = waves x 0.86.
// The grid was wave-starved (4096 waves = 16/CU = half of what VGPR allows).
// Fix: TWO waves per sequence (vocab split: wave h owns elems [64h,64h+64),
// one dword/lane) -> 8192 waves = 32/CU. Per-step cross-wave argmax exchange
// via LDS + RAW s_barrier (never __syncthreads - it drains vmcnt and would
// serialize the pipeline). Asm register ring (D=14) with exact vmcnt ledger.
// VGPR must stay <=64 for 8 waves/SIMD: ring+fbuf = 30 regs, total ~55.

constexpr int V = 128;
constexpr int L = 128;
constexpr int N = 4096;
constexpr int D  = 14;      // rows in flight per wave
constexpr int RD = D + 1;   // ring slots (hoisted prefetch needs +1)
constexpr unsigned ROWB = (unsigned)N * V * 4;  // 2 MiB between rows

// Full-wave max (64 lanes), result broadcast to all lanes.
__device__ __forceinline__ float wave_max_dpp(float x) {
    int v = __float_as_int(x);
    const int ninf = __float_as_int(-__builtin_inff());
#define RF_STEP(ctrl)                                                          \
    {                                                                          \
        int s = __builtin_amdgcn_update_dpp(ninf, v, ctrl, 0xf, 0xf, false);   \
        v = __float_as_int(fmaxf(__int_as_float(v), __int_as_float(s)));       \
    }
    RF_STEP(0x111)  // row_shr:1
    RF_STEP(0x112)  // row_shr:2
    RF_STEP(0x114)  // row_shr:4
    RF_STEP(0x118)  // row_shr:8
    RF_STEP(0x142)  // row_bcast:15
    RF_STEP(0x143)  // row_bcast:31 -> lane63 = max(all 64)
#undef RF_STEP
    return __int_as_float(__builtin_amdgcn_readlane(v, 63));
}

// Wave-uniform pointer -> SGPR-provable uniform value (readfirstlane launder).
__device__ __forceinline__ unsigned long long uniform_u64(const void* p) {
    unsigned long long x = (unsigned long long)p;
    unsigned lo = __builtin_amdgcn_readfirstlane((unsigned)x);
    unsigned hi = __builtin_amdgcn_readfirstlane((unsigned)(x >> 32));
    return ((unsigned long long)hi << 32) | lo;
}

// One fully-unrolled pipeline step; all indices compile-time (SROA -> VGPRs).
template <int I>
struct Step {
    static __device__ __forceinline__ void run(float* ring, float* fbuf,
                                               const unsigned* tbl, int& prev,
                                               int hbase,
                                               unsigned long long lbase,
                                               unsigned long long obase,
                                               unsigned laneoff,
                                               unsigned xwa, unsigned xra) {
        // vmcnt ledger. Step order: [prefetch L_{I+D}], wait(L_I), compute,
        // store S_I, exchange. Ops strictly newer than L_I at the wait:
        //   loads L_{I+1}..L_{min(I+D,L-1)}  = min(D, L-1-I)
        //   stores S_{max(0,I-D)}..S_{I-1}   = min(I, D)
        // (L_I is issued BEFORE S_{I-D} in step I-D, so S_{I-D} is newer.)
        constexpr int NW = ((L - 1 - I) < D ? (L - 1 - I) : D) + (I < D ? I : D);
        constexpr int rs = I % RD;

        // Hoisted prefetch: slot (I+D)%RD was consumed at step I-1 (RD=D+1).
        if constexpr (I + D < L) {
            constexpr int ps = (I + D) % RD;
            unsigned voff = (unsigned)(I + D) * ROWB + laneoff;
            asm volatile("global_load_dword %0, %1, %2"
                         : "=&v"(ring[ps])
                         : "v"(voff), "s"(lbase));
        }

        // Ties: ring[rs] -> consumers ordered after the wait; fbuf[rs] ->
        // the RD-step-old store's data reg stays alive until provably retired.
        asm volatile("s_waitcnt vmcnt(%c2)"
                     : "+v"(ring[rs])
                     : "v"(fbuf[rs]), "i"(NW));

        float c = ring[rs];
        float f;
        if constexpr (I == 0) {
            f = c;  // row 0 passes through unfiltered
        } else {
            // Column-major per-lane table: bit p of tbl = allow(prev=p, my elem)
            unsigned t01  = (prev & 32) ? tbl[1] : tbl[0];
            unsigned t23  = (prev & 32) ? tbl[3] : tbl[2];
            unsigned word = (prev & 64) ? t23 : t01;
            unsigned bit  = (word >> (prev & 31)) & 1u;
            f = __int_as_float(__float_as_int(c) & (0u - bit));  // exact +0.0
        }
        fbuf[rs] = f;

        {
            unsigned voff = (unsigned)I * ROWB + laneoff;
            asm volatile("global_store_dword %0, %1, %2"
                         :
                         : "v"(voff), "v"(fbuf[rs]), "s"(obase));
        }

        if constexpr (I < L - 1) {
            // Half-argmax: 1 elem/lane -> ladder + ballot + ctz.
            float bv = wave_max_dpp(f);
            unsigned long long blt = __ballot(f == bv);
            int im = hbase + (__ffsll((unsigned long long)blt) - 1);

            // Cross-wave exchange. Parity-double-buffered slots; one RAW
            // barrier per step (lgkmcnt-only wait -> vmcnt pipeline survives).
            unsigned long long pk =
                ((unsigned long long)(unsigned)im << 32) |
                (unsigned)__float_as_int(bv);
            constexpr int PAR = (I & 1) * 1024;  // byte offset of parity buffer
            asm volatile("ds_write_b64 %0, %1 offset:%c2"
                         :: "v"(xwa), "v"(pk), "i"(PAR));
            asm volatile("s_waitcnt lgkmcnt(0)");
            __builtin_amdgcn_s_barrier();
            unsigned long long got;
            asm volatile("ds_read_b64 %0, %1 offset:%c2"
                         : "=v"(got)
                         : "v"(xra), "i"(PAR));
            asm volatile("s_waitcnt lgkmcnt(0)" : "+v"(got));
            __builtin_amdgcn_sched_barrier(0);  // rule 18: pin consumers

            float bo = __int_as_float((int)(unsigned)(got & 0xFFFFFFFFull));
            int   io = (int)(got >> 32);
            bool take = (bo > bv) || ((bo == bv) && (io < im));
            prev = take ? io : im;
        }

        Step<I + 1>::run(ring, fbuf, tbl, prev, hbase, lbase, obase, laneoff,
                         xwa, xra);
    }
};
template <>
struct Step<L> {
    static __device__ __forceinline__ void run(float*, float*, const unsigned*,
                                               int&, int, unsigned long long,
                                               unsigned long long, unsigned,
                                               unsigned, unsigned) {}
};

__global__ __launch_bounds__(128, 8) void rule_filter_kernel(
    const float* __restrict__ logits,      // (L, N, V)
    const float* __restrict__ mask_table,  // (V, V)
    float* __restrict__ out)               // (L, N, V)
{
    // [parity][wave h][lane] -> 2 KiB; 16 blocks/CU x 2 KiB = 32 KiB.
    __shared__ unsigned long long xch[2][2][64];

    const int h    = threadIdx.x >> 6;  // 0..1: vocab half
    const int lane = threadIdx.x & 63;
    const int n    = blockIdx.x;        // sequence
    const int e    = h * 64 + lane;     // my vocab element

    const unsigned long long lbase = uniform_u64(logits + (size_t)n * V);
    const unsigned long long obase = uniform_u64(out    + (size_t)n * V);
    const unsigned laneoff = (unsigned)e * 4;

    // Column-major mask table: tbl[w] bit b = (mask_table[32w+b][e] != 0).
    // Loads are coalesced across the wave (consecutive e) for each prev row.
    unsigned tbl[4];
#pragma unroll 1
    for (int w = 0; w < 4; ++w) {
        unsigned acc = 0;
#pragma unroll
        for (int b = 0; b < 32; ++b) {
            float m = mask_table[(size_t)(w * 32 + b) * V + e];
            acc |= (m != 0.0f ? 1u : 0u) << b;
        }
        tbl[w] = acc;
    }
    // Drain table loads so the hand-counted vmcnt ledger is exact.
    asm volatile("s_waitcnt vmcnt(0)" ::: "memory");

    float ring[RD];
    float fbuf[RD];
#pragma unroll
    for (int r = 0; r < RD; ++r) fbuf[r] = 0.0f;

    // Prologue: rows 0..D-1 into ring[0..D-1] (vmcnt ops 1..D, in order).
#pragma unroll
    for (int r = 0; r < D; ++r) {
        unsigned voff = (unsigned)r * ROWB + laneoff;
        asm volatile("global_load_dword %0, %1, %2"
                     : "=&v"(ring[r])
                     : "v"(voff), "s"(lbase));
    }

    const unsigned xwa = (unsigned)(unsigned long long)&xch[0][h][lane];
    const unsigned xra = (unsigned)(unsigned long long)&xch[0][1 - h][lane];

    int prev = 0;
    Step<0>::run(ring, fbuf, tbl, prev, h * 64, lbase, obase, laneoff, xwa, xra);
}

extern "C" void kernel_launch(void* const* d_in, const int* in_sizes, int n_in,
                              void* d_out, int out_size, void* d_ws, size_t ws_size,
                              hipStream_t stream) {
    const float* logits     = (const float*)d_in[0];  // (L, N, V) fp32
    const float* mask_table = (const float*)d_in[1];  // (V, V) fp32
    float* out              = (float*)d_out;          // (L, N, V) fp32

    dim3 grid(N);     // one 2-wave block per sequence -> 8192 waves
    dim3 block(128);
    rule_filter_kernel<<<grid, block, 0, stream>>>(logits, mask_table, out);
}